// Round 3
// baseline (239.876 us; speedup 1.0000x reference)
//
#include <hip/hip_runtime.h>
#include <stdint.h>

// KANLinear fused MFMA GEMM, R8: B operand direct from L2 into registers.
//   R6/R7 post-mortem: LDS BW was the wall (192 ds_read_b128/chunk/CU = 2304 cyc
//   vs 1242 cyc MFMA). Wc is L2-resident (1.18 MB) -> load B frags straight to
//   VGPRs (reg-dbuf, rolled per kk-half); LDS holds only the A-expansion (32 KB).
//   128x256 tile, 1024 thr / 16 waves (4 waves/SIMD TLP), per-wave 32x64.
//   C = A @ W^T, A (B x 2304) = [silu(x) | bases(x)], W (256 x 2304) bf16 in ws.

#define IN_F 256
#define OUT_F 256
#define KDIM 2304 /* 256 silu + 256*8 basis */
#define BK 64
#define NCHUNK (KDIM / BK) /* 36, even */
#define TBINS 512
#define NTAB (11 * TBINS)     /* 5632 real entries (j0 0..10 x 512 bins) */
#define NTAB_PAD (NTAB + 2)   /* zero guard rows at both ends */
#define WC_BYTES ((size_t)OUT_F * KDIM * 2) /* 1,179,648 (16-aligned) */

#define AS1 __attribute__((address_space(1)))
#define AS3 __attribute__((address_space(3)))

typedef float f32x4 __attribute__((ext_vector_type(4)));
typedef short bf16x8 __attribute__((ext_vector_type(8)));

__device__ __forceinline__ uint32_t f2bf(float f) {
    union { float f; uint32_t u; } c; c.f = f;
    uint32_t u = c.u;
    return (u + 0x7FFFu + ((u >> 16) & 1u)) >> 16;   // RNE
}

__device__ __forceinline__ float silu_f(float v) {
    return v / (1.0f + __expf(-v));
}

// ---------------- kernel 1: bf16 weight + full-range basis table ----------------
__global__ void build_w(const float* __restrict__ bw, const float* __restrict__ sw,
                        const float* __restrict__ ss, unsigned short* __restrict__ Wc,
                        uint4* __restrict__ tgt) {
    const int o = blockIdx.x;
    const int i = threadIdx.x;
    Wc[o * KDIM + i] = (unsigned short)f2bf(bw[o * IN_F + i]);
    const float scal = ss[o * IN_F + i];
    const float4* swv = reinterpret_cast<const float4*>(sw + (size_t)(o * IN_F + i) * 8);
    float4 s0 = swv[0], s1 = swv[1];
    uint4 wv;
    wv.x = f2bf(s0.x * scal) | (f2bf(s0.y * scal) << 16);
    wv.y = f2bf(s0.z * scal) | (f2bf(s0.w * scal) << 16);
    wv.z = f2bf(s1.x * scal) | (f2bf(s1.y * scal) << 16);
    wv.w = f2bf(s1.z * scal) | (f2bf(s1.w * scal) << 16);
    *reinterpret_cast<uint4*>(Wc + o * KDIM + IN_F + i * 8) = wv;

    if (o == 0) {
        // entry e=0 and e=NTAB+1 are zero rows (out-of-grid clamp targets).
        // entry e=idx+1, idx = j0*512+bin: 8 bf16 coef slots, p[m] at slot j0-3+m.
        for (int e = i; e < NTAB_PAD; e += IN_F) {
            uint32_t h[4] = {0u, 0u, 0u, 0u};
            if (e >= 1 && e <= NTAB) {
                const int idx = e - 1;
                const int j0 = idx >> 9;
                const float t = ((idx & (TBINS - 1)) + 0.5f) * (1.0f / TBINS);
                const float t2 = t * t, t3 = t2 * t;
                float p[4];
                p[3] = t3 * (1.0f / 6.0f);
                p[2] = -0.5f * t3 + 0.5f * t2 + 0.5f * t + (1.0f / 6.0f);
                p[1] = 0.5f * t3 - t2 + (2.0f / 3.0f);
                const float omt = 1.0f - t;
                p[0] = omt * omt * omt * (1.0f / 6.0f);
#pragma unroll
                for (int m = 0; m < 4; ++m) {
                    int c = j0 - 3 + m;
                    if (c >= 0 && c < 8) h[c >> 1] |= f2bf(p[m]) << ((c & 1) * 16);
                }
            }
            uint4 e4; e4.x = h[0]; e4.y = h[1]; e4.z = h[2]; e4.w = h[3];
            tgt[e] = e4;
        }
    }
}

// ---------------- kernel 2: fused GEMM, 1024 threads, B from L2 ----------------
// A LDS layout per tile: addr(row, g) = row*128B + ((g ^ (row&7))*16B), g = k/8
__launch_bounds__(1024, 4)
__global__ void kan_fused(const float* __restrict__ x, const unsigned short* __restrict__ Wc,
                          const uint4* __restrict__ tgt, float* __restrict__ out) {
    __shared__ __align__(16) unsigned short As[2][128 * 64];   // 32 KB total

    const int bid = blockIdx.x;
    const int row0 = bid * 128;
    const int tid = threadIdx.x;
    const int lane = tid & 63;
    const int w = tid >> 6;            // wave id 0..15
    const int wm = w >> 2;             // 0..3 : 32-row band
    const int wn = w & 3;              // 0..3 : 64-col quarter
    const int l15 = lane & 15;
    const int q = lane >> 4;

    // A staging mapping: thread owns (row arow, logical k-segment g), 16 B/chunk
    const int sr = lane >> 3;          // row within 8-row group
    const int s  = lane & 7;           // physical 16B segment
    const int g  = s ^ sr;             // logical k-segment held by this thread
    const int arow = w * 8 + sr;       // A stage row 0..127

    f32x4 acc[2][4] = {};
    uint4 pkE, pkO;                    // A-expansion pipeline (packed bf16x8)
    bf16x8 bA[4], bB[4];               // B fragment register double-buffer

    // per-lane B row base: rows wn*64 + nt*16 + l15, k-offset q*8 within a frag
    const unsigned short* wrow = Wc + (size_t)(wn * 64 + l15) * KDIM + q * 8;

    auto load_b = [&](bf16x8* dst, int kc, int kk) {
#pragma unroll
        for (int nt = 0; nt < 4; ++nt)
            dst[nt] = *reinterpret_cast<const bf16x8*>(
                wrow + (size_t)nt * (16 * KDIM) + kc * BK + kk);
    };
    auto load_x = [&](int c, uint4& pk) {
        if (c < 4) {
            const float* xp = x + (size_t)(row0 + arow) * IN_F + c * 64 + g * 8;
            float4 a = *reinterpret_cast<const float4*>(xp);
            float4 b = *reinterpret_cast<const float4*>(xp + 4);
            pk.x = f2bf(silu_f(a.x)) | (f2bf(silu_f(a.y)) << 16);
            pk.y = f2bf(silu_f(a.z)) | (f2bf(silu_f(a.w)) << 16);
            pk.z = f2bf(silu_f(b.x)) | (f2bf(silu_f(b.y)) << 16);
            pk.w = f2bf(silu_f(b.z)) | (f2bf(silu_f(b.w)) << 16);
        } else {
            const int i0 = (c - 4) * 8 + g;
            float xx = x[(size_t)(row0 + arow) * IN_F + i0];
            float u = __builtin_fmaf(xx, 2.5f, 5.5f);   // (x - grid0)/h
            int ic = (int)floorf(u * (float)TBINS);
            ic = ic < -1 ? -1 : (ic > NTAB ? NTAB : ic); // guards are zero rows
            pk = tgt[ic + 1];                            // pre-positioned bf16x8 row
        }
    };
    auto write_a = [&](int buf, const uint4& pk) {
        *reinterpret_cast<uint4*>(&As[buf][arow * 64 + s * 8]) = pk;
    };
    auto mfma_kk = [&](int cur, int kk, const bf16x8* bv) {
        bf16x8 af[2];
        const int g0 = (kk >> 3) + q;
#pragma unroll
        for (int mt = 0; mt < 2; ++mt) {
            int r = wm * 32 + mt * 16 + l15;
            af[mt] = *reinterpret_cast<const bf16x8*>(
                &As[cur][r * 64 + ((g0 ^ (r & 7)) << 3)]);
        }
        __builtin_amdgcn_s_setprio(1);
#pragma unroll
        for (int mt = 0; mt < 2; ++mt)
#pragma unroll
            for (int nt = 0; nt < 4; ++nt)
                acc[mt][nt] = __builtin_amdgcn_mfma_f32_16x16x32_bf16(
                    af[mt], bv[nt], acc[mt][nt], 0, 0, 0);
        __builtin_amdgcn_s_setprio(0);
    };

    // prologue: A(0) expanded+written, A(1) expansion in flight, B(0,kk0) in regs
    load_x(0, pkE);
    write_a(0, pkE);
    load_x(1, pkO);
    load_b(bA, 0, 0);
    __syncthreads();

    // steady state, parity-unrolled x2 (static buffer/reg-set naming):
    //   chunk c: {load bB<-B(c,32); issue expand(c+2); MFMA kk0 (bA);
    //             load bA<-B(c+1,0); MFMA kk32 (bB); write A(c+1); barrier}
    for (int kc = 0; kc < NCHUNK; kc += 2) {
        {   // chunk kc (even), A buf 0
            load_b(bB, kc, 32);
            if (kc + 2 < NCHUNK) load_x(kc + 2, pkE);
            mfma_kk(0, 0, bA);
            if (kc + 1 < NCHUNK) load_b(bA, kc + 1, 0);
            mfma_kk(0, 32, bB);
            if (kc + 1 < NCHUNK) write_a(1, pkO);
            __syncthreads();
        }
        {   // chunk kc+1 (odd), A buf 1
            load_b(bB, kc + 1, 32);
            if (kc + 3 < NCHUNK) load_x(kc + 3, pkO);
            mfma_kk(1, 0, bA);
            if (kc + 2 < NCHUNK) load_b(bA, kc + 2, 0);
            mfma_kk(1, 32, bB);
            if (kc + 2 < NCHUNK) write_a(0, pkE);
            __syncthreads();
        }
    }

    // epilogue: C/D layout col = lane&15, row = (lane>>4)*4 + reg
#pragma unroll
    for (int mt = 0; mt < 2; ++mt) {
        int row = row0 + wm * 32 + mt * 16 + q * 4;
#pragma unroll
        for (int nt = 0; nt < 4; ++nt) {
            int col = wn * 64 + nt * 16 + l15;
#pragma unroll
            for (int r = 0; r < 4; ++r)
                out[(size_t)(row + r) * OUT_F + col] = acc[mt][nt][r];
        }
    }
}

extern "C" void kernel_launch(void* const* d_in, const int* in_sizes, int n_in,
                              void* d_out, int out_size, void* d_ws, size_t ws_size,
                              hipStream_t stream) {
    const float* x  = (const float*)d_in[0];
    const float* bw = (const float*)d_in[1];
    const float* sw = (const float*)d_in[2];
    const float* ss = (const float*)d_in[3];
    unsigned short* Wc = (unsigned short*)d_ws;                 // 1.18 MB
    uint4* tgt = (uint4*)((char*)d_ws + WC_BYTES);              // 90 KB table

    build_w<<<dim3(OUT_F), dim3(IN_F), 0, stream>>>(bw, sw, ss, Wc, tgt);

    const int B_ROWS = in_sizes[0] / IN_F;                      // 32768
    kan_fused<<<dim3(B_ROWS / 128), dim3(1024), 0, stream>>>(
        x, Wc, tgt, (float*)d_out);
}

// Round 4
// 231.392 us; speedup vs baseline: 1.0367x; 1.0367x over previous
//
#include <hip/hip_runtime.h>
#include <stdint.h>

// KANLinear fused MFMA GEMM, R9: A expanded DIRECTLY into MFMA fragments.
//   Structural insight: for the basis region, lane (q,l15) of an A fragment is
//   exactly one 16B pre-positioned table entry tgt[bin(x[row, feat])] -- the
//   gather IS the fragment. Silu region: lane packs silu(x[row, k..k+7]) itself.
//   => A never touches LDS. LDS holds only B (dbuf 64 KB static).
//   128x256 tile, 512 thr / 8 waves (2x4), wave-tile 64x64. Gathers issued one
//   full chunk (~1250 cyc) ahead into parity register sets (R8's vmcnt lesson).
//   C = A @ W^T, A (B x 2304) = [silu(x) | bases(x)], W (256 x 2304) bf16 in ws.

#define IN_F 256
#define OUT_F 256
#define KDIM 2304 /* 256 silu + 256*8 basis */
#define BK 64
#define NCHUNK (KDIM / BK) /* 36, even */
#define TBINS 512
#define NTAB (11 * TBINS)     /* 5632 real entries (j0 0..10 x 512 bins) */
#define NTAB_PAD (NTAB + 2)   /* zero guard rows at both ends */
#define WC_BYTES ((size_t)OUT_F * KDIM * 2) /* 1,179,648 (16-aligned) */

#define AS1 __attribute__((address_space(1)))
#define AS3 __attribute__((address_space(3)))

typedef float f32x4 __attribute__((ext_vector_type(4)));
typedef short bf16x8 __attribute__((ext_vector_type(8)));

__device__ __forceinline__ uint32_t f2bf(float f) {
    union { float f; uint32_t u; } c; c.f = f;
    uint32_t u = c.u;
    return (u + 0x7FFFu + ((u >> 16) & 1u)) >> 16;   // RNE
}

__device__ __forceinline__ float silu_f(float v) {
    return v / (1.0f + __expf(-v));
}

// ---------------- kernel 1: bf16 weight + full-range basis table ----------------
__global__ void build_w(const float* __restrict__ bw, const float* __restrict__ sw,
                        const float* __restrict__ ss, unsigned short* __restrict__ Wc,
                        uint4* __restrict__ tgt) {
    const int o = blockIdx.x;
    const int i = threadIdx.x;
    Wc[o * KDIM + i] = (unsigned short)f2bf(bw[o * IN_F + i]);
    const float scal = ss[o * IN_F + i];
    const float4* swv = reinterpret_cast<const float4*>(sw + (size_t)(o * IN_F + i) * 8);
    float4 s0 = swv[0], s1 = swv[1];
    uint4 wv;
    wv.x = f2bf(s0.x * scal) | (f2bf(s0.y * scal) << 16);
    wv.y = f2bf(s0.z * scal) | (f2bf(s0.w * scal) << 16);
    wv.z = f2bf(s1.x * scal) | (f2bf(s1.y * scal) << 16);
    wv.w = f2bf(s1.z * scal) | (f2bf(s1.w * scal) << 16);
    *reinterpret_cast<uint4*>(Wc + o * KDIM + IN_F + i * 8) = wv;

    if (o == 0) {
        // entry e=0 and e=NTAB+1 are zero rows (out-of-grid clamp targets).
        // entry e=idx+1, idx = j0*512+bin: 8 bf16 coef slots, p[m] at slot j0-3+m.
        for (int e = i; e < NTAB_PAD; e += IN_F) {
            uint32_t h[4] = {0u, 0u, 0u, 0u};
            if (e >= 1 && e <= NTAB) {
                const int idx = e - 1;
                const int j0 = idx >> 9;
                const float t = ((idx & (TBINS - 1)) + 0.5f) * (1.0f / TBINS);
                const float t2 = t * t, t3 = t2 * t;
                float p[4];
                p[3] = t3 * (1.0f / 6.0f);
                p[2] = -0.5f * t3 + 0.5f * t2 + 0.5f * t + (1.0f / 6.0f);
                p[1] = 0.5f * t3 - t2 + (2.0f / 3.0f);
                const float omt = 1.0f - t;
                p[0] = omt * omt * omt * (1.0f / 6.0f);
#pragma unroll
                for (int m = 0; m < 4; ++m) {
                    int c = j0 - 3 + m;
                    if (c >= 0 && c < 8) h[c >> 1] |= f2bf(p[m]) << ((c & 1) * 16);
                }
            }
            uint4 e4; e4.x = h[0]; e4.y = h[1]; e4.z = h[2]; e4.w = h[3];
            tgt[e] = e4;
        }
    }
}

// ---------------- kernel 2: fused GEMM, 512 threads, A in registers ----------------
// B LDS layout per tile: addr(row, g) = row*128B + ((g ^ (row&7))*16B), g = k/8
__launch_bounds__(512, 2)
__global__ void kan_fused(const float* __restrict__ x, const unsigned short* __restrict__ Wc,
                          const uint4* __restrict__ tgt, float* __restrict__ out) {
    __shared__ __align__(16) unsigned short Bs[2][256 * 64];   // 64 KB

    const int bid = blockIdx.x;
    const int row0 = bid * 128;
    const int tid = threadIdx.x;
    const int lane = tid & 63;
    const int w = tid >> 6;            // wave id 0..7
    const int wm = w >> 2;             // 0..1 : 64-row half
    const int wn = w & 3;              // 0..3 : 64-col quarter
    const int l15 = lane & 15;
    const int q = lane >> 4;

    // B staging mapping: thread owns (row brow+j*8, logical k-seg g), 4x16B/chunk
    const int sr = lane >> 3;          // row within 8-row group
    const int s  = lane & 7;           // physical 16B segment
    const int g  = s ^ sr;             // logical k-segment held by this thread
    const int brow = w * 32 + sr;      // B stage row base (+ j*8, j=0..3)

    f32x4 acc[4][4] = {};              // [mt][nt], wave-tile 64x64
    bf16x8 afE[2][4], afO[2][4];       // A fragments [kkh][mt], parity sets

    auto stage_b = [&](int kc, int buf) {
#pragma unroll
        for (int j = 0; j < 4; ++j) {
            const unsigned short* gp =
                Wc + (size_t)(brow + j * 8) * KDIM + kc * BK + g * 8;
            __builtin_amdgcn_global_load_lds((const AS1 void*)gp,
                (AS3 void*)(&Bs[buf][(w * 32 + j * 8) * 64]), 16, 0, 0);
        }
    };

    // expand A-fragments of chunk kc straight into registers (no LDS):
    //   fragment (kkh, mt), lane (q, l15):
    //     row = row0 + wm*64 + mt*16 + l15
    //     silu  (kc<4): k = kc*64 + kkh*32 + q*8, af = pack(silu(x[row, k..k+7]))
    //     basis (kc>=4): feat = kc*8 + kkh*4 + q - 32, af = tgt[bin(x[row,feat])]
    auto prefetch = [&](int kc, bf16x8 (&dst)[2][4]) {
        if (kc < 4) {
#pragma unroll
            for (int kkh = 0; kkh < 2; ++kkh)
#pragma unroll
                for (int mt = 0; mt < 4; ++mt) {
                    const int row = row0 + wm * 64 + mt * 16 + l15;
                    const float* xp = x + (size_t)row * IN_F + kc * 64 + kkh * 32 + q * 8;
                    float4 a = *reinterpret_cast<const float4*>(xp);
                    float4 b = *reinterpret_cast<const float4*>(xp + 4);
                    uint4 wv;
                    wv.x = f2bf(silu_f(a.x)) | (f2bf(silu_f(a.y)) << 16);
                    wv.y = f2bf(silu_f(a.z)) | (f2bf(silu_f(a.w)) << 16);
                    wv.z = f2bf(silu_f(b.x)) | (f2bf(silu_f(b.y)) << 16);
                    wv.w = f2bf(silu_f(b.z)) | (f2bf(silu_f(b.w)) << 16);
                    dst[kkh][mt] = *reinterpret_cast<bf16x8*>(&wv);
                }
        } else {
#pragma unroll
            for (int kkh = 0; kkh < 2; ++kkh)
#pragma unroll
                for (int mt = 0; mt < 4; ++mt) {
                    const int row = row0 + wm * 64 + mt * 16 + l15;
                    const int feat = kc * 8 + kkh * 4 + q - 32;
                    float xx = x[(size_t)row * IN_F + feat];
                    float u = __builtin_fmaf(xx, 2.5f, 5.5f);   // (x - grid0)/h
                    int ic = (int)floorf(u * (float)TBINS);
                    ic = ic < -1 ? -1 : (ic > NTAB ? NTAB : ic); // guard rows = 0
                    uint4 t = tgt[ic + 1];                       // positioned bf16x8
                    dst[kkh][mt] = *reinterpret_cast<bf16x8*>(&t);
                }
        }
    };

    auto mfma_chunk = [&](int cur, const bf16x8 (&af)[2][4]) {
        bf16x8 bfv[2][4];
#pragma unroll
        for (int kkh = 0; kkh < 2; ++kkh) {
            const int g0 = kkh * 4 + q;
#pragma unroll
            for (int nt = 0; nt < 4; ++nt) {
                int r = wn * 64 + nt * 16 + l15;
                bfv[kkh][nt] = *reinterpret_cast<const bf16x8*>(
                    &Bs[cur][r * 64 + ((g0 ^ (r & 7)) << 3)]);
            }
        }
        __builtin_amdgcn_s_setprio(1);
#pragma unroll
        for (int kkh = 0; kkh < 2; ++kkh)
#pragma unroll
            for (int mt = 0; mt < 4; ++mt)
#pragma unroll
                for (int nt = 0; nt < 4; ++nt)
                    acc[mt][nt] = __builtin_amdgcn_mfma_f32_16x16x32_bf16(
                        af[kkh][mt], bfv[kkh][nt], acc[mt][nt], 0, 0, 0);
        __builtin_amdgcn_s_setprio(0);
    };

    // prologue: B(0) staged, A(0) fragments gathered
    stage_b(0, 0);
    prefetch(0, afE);
    __syncthreads();

    // steady state, parity-unrolled x2 (static reg-set naming):
    //   chunk kc: {stage B(kc+1); issue A-gathers(kc+1)->other set;
    //              8 ds_read_b128 + 32 MFMA on current set; barrier}
    for (int kc = 0; kc < NCHUNK; kc += 2) {
        {   // chunk kc (even): uses afE, Bs[0]
            if (kc + 1 < NCHUNK) { stage_b(kc + 1, 1); prefetch(kc + 1, afO); }
            mfma_chunk(0, afE);
            __syncthreads();
        }
        {   // chunk kc+1 (odd): uses afO, Bs[1]
            if (kc + 2 < NCHUNK) { stage_b(kc + 2, 0); prefetch(kc + 2, afE); }
            mfma_chunk(1, afO);
            __syncthreads();
        }
    }

    // epilogue: C/D layout col = lane&15, row = (lane>>4)*4 + reg
#pragma unroll
    for (int mt = 0; mt < 4; ++mt) {
        int row = row0 + wm * 64 + mt * 16 + q * 4;
#pragma unroll
        for (int nt = 0; nt < 4; ++nt) {
            int col = wn * 64 + nt * 16 + l15;
#pragma unroll
            for (int r = 0; r < 4; ++r)
                out[(size_t)(row + r) * OUT_F + col] = acc[mt][nt][r];
        }
    }
}

extern "C" void kernel_launch(void* const* d_in, const int* in_sizes, int n_in,
                              void* d_out, int out_size, void* d_ws, size_t ws_size,
                              hipStream_t stream) {
    const float* x  = (const float*)d_in[0];
    const float* bw = (const float*)d_in[1];
    const float* sw = (const float*)d_in[2];
    const float* ss = (const float*)d_in[3];
    unsigned short* Wc = (unsigned short*)d_ws;                 // 1.18 MB
    uint4* tgt = (uint4*)((char*)d_ws + WC_BYTES);              // 90 KB table

    build_w<<<dim3(OUT_F), dim3(IN_F), 0, stream>>>(bw, sw, ss, Wc, tgt);

    const int B_ROWS = in_sizes[0] / IN_F;                      // 32768
    kan_fused<<<dim3(B_ROWS / 128), dim3(512), 0, stream>>>(
        x, Wc, tgt, (float*)d_out);
}

// Round 5
// 155.688 us; speedup vs baseline: 1.5407x; 1.4863x over previous
//
#include <hip/hip_runtime.h>
#include <stdint.h>

// KANLinear fused MFMA GEMM, R10: split memory systems by their strengths.
//   R7 lesson: LDS port wall when A+B both in LDS (176KB/chunk ≈ 2100cyc).
//   R8 lesson: B-from-global same-phase = fatal vmcnt serialization.
//   R9 lesson: per-lane divergent gathers (4096 txns/chunk) choke the TA/L1 port.
//   => A expanded ONCE cooperatively via LDS (1024 gathers, 80KB LDS/chunk);
//      B direct L2->registers ONE CHUNK AHEAD, coalesced via a fragment-native
//      Wc layout (each 64-lane x 16B B-fragment stored as one contiguous 1KB).
//   128x256 tile, 512 thr / 8 waves (2x4), wave-tile 64x64, grid 256 (1 blk/CU).
//   C = A @ W^T, A (B x 2304) = [silu(x) | bases(x)], W (256 x 2304) bf16 in ws.

#define IN_F 256
#define OUT_F 256
#define KDIM 2304 /* 256 silu + 256*8 basis */
#define BK 64
#define NCHUNK (KDIM / BK) /* 36, even */
#define TBINS 512
#define NTAB (11 * TBINS)     /* 5632 real entries (j0 0..10 x 512 bins) */
#define NTAB_PAD (NTAB + 2)   /* zero guard rows at both ends */
#define WC_BYTES ((size_t)OUT_F * KDIM * 2) /* 1,179,648 (16-aligned) */

typedef float f32x4 __attribute__((ext_vector_type(4)));
typedef short bf16x8 __attribute__((ext_vector_type(8)));

__device__ __forceinline__ uint32_t f2bf(float f) {
    union { float f; uint32_t u; } c; c.f = f;
    uint32_t u = c.u;
    return (u + 0x7FFFu + ((u >> 16) & 1u)) >> 16;   // RNE
}

__device__ __forceinline__ float silu_f(float v) {
    return v / (1.0f + __expf(-v));
}

// fragment-native Wc address (in bf16 units) for element
//   W[col][kc*64 + kkh*32 + q*8 + e],  col = c16*16 + l15:
//   ((kc*2+kkh)*16 + c16)*512 + (q*16 + l15)*8 + e
__device__ __forceinline__ size_t wcf_addr(int col, int k) {
    const int kc = k >> 6, kkh = (k >> 5) & 1, q = (k >> 3) & 3, e = k & 7;
    return ((size_t)((kc * 2 + kkh) * 16 + (col >> 4))) * 512 +
           (size_t)(q * 16 + (col & 15)) * 8 + e;
}

// ---------------- kernel 1: fragment-native bf16 weight + basis table ----------------
__global__ void build_w(const float* __restrict__ bw, const float* __restrict__ sw,
                        const float* __restrict__ ss, unsigned short* __restrict__ WcF,
                        uint4* __restrict__ tgt) {
    const int o = blockIdx.x;    // output col 0..255
    const int i = threadIdx.x;   // input feature 0..255
    // base region: k = i (scalar scatter, one-time kernel)
    WcF[wcf_addr(o, i)] = (unsigned short)f2bf(bw[o * IN_F + i]);
    // spline region: k0 = 256 + i*8 (one aligned 16B fragment slice)
    const float scal = ss[o * IN_F + i];
    const float4* swv = reinterpret_cast<const float4*>(sw + (size_t)(o * IN_F + i) * 8);
    float4 s0 = swv[0], s1 = swv[1];
    uint4 wv;
    wv.x = f2bf(s0.x * scal) | (f2bf(s0.y * scal) << 16);
    wv.y = f2bf(s0.z * scal) | (f2bf(s0.w * scal) << 16);
    wv.z = f2bf(s1.x * scal) | (f2bf(s1.y * scal) << 16);
    wv.w = f2bf(s1.z * scal) | (f2bf(s1.w * scal) << 16);
    *reinterpret_cast<uint4*>(WcF + wcf_addr(o, IN_F + i * 8)) = wv;

    if (o == 0) {
        // entry e=0 and e=NTAB+1 are zero rows (out-of-grid clamp targets).
        // entry e=idx+1, idx = j0*512+bin: 8 bf16 coef slots, p[m] at slot j0-3+m.
        for (int e = i; e < NTAB_PAD; e += IN_F) {
            uint32_t h[4] = {0u, 0u, 0u, 0u};
            if (e >= 1 && e <= NTAB) {
                const int idx = e - 1;
                const int j0 = idx >> 9;
                const float t = ((idx & (TBINS - 1)) + 0.5f) * (1.0f / TBINS);
                const float t2 = t * t, t3 = t2 * t;
                float p[4];
                p[3] = t3 * (1.0f / 6.0f);
                p[2] = -0.5f * t3 + 0.5f * t2 + 0.5f * t + (1.0f / 6.0f);
                p[1] = 0.5f * t3 - t2 + (2.0f / 3.0f);
                const float omt = 1.0f - t;
                p[0] = omt * omt * omt * (1.0f / 6.0f);
#pragma unroll
                for (int m = 0; m < 4; ++m) {
                    int c = j0 - 3 + m;
                    if (c >= 0 && c < 8) h[c >> 1] |= f2bf(p[m]) << ((c & 1) * 16);
                }
            }
            uint4 e4; e4.x = h[0]; e4.y = h[1]; e4.z = h[2]; e4.w = h[3];
            tgt[e] = e4;
        }
    }
}

// ---------------- kernel 2: fused GEMM, 512 threads ----------------
// A LDS layout per tile: addr(row, g) = row*128B + ((g ^ (row&7))*16B), g = k/8
__launch_bounds__(512, 2)
__global__ void kan_fused(const float* __restrict__ x, const unsigned short* __restrict__ WcF,
                          const uint4* __restrict__ tgt, float* __restrict__ out) {
    __shared__ __align__(16) unsigned short As[2][128 * 64];   // 32 KB

    const int bid = blockIdx.x;
    const int row0 = bid * 128;
    const int tid = threadIdx.x;
    const int lane = tid & 63;
    const int w = tid >> 6;            // wave id 0..7
    const int wm = w >> 2;             // 0..1 : 64-row half
    const int wn = w & 3;              // 0..3 : 64-col quarter
    const int l15 = lane & 15;
    const int q = lane >> 4;

    // cooperative A-expansion thread mapping (each element exactly once):
    const int erow = tid & 127;        // basis: row 0..127
    const int efp  = tid >> 7;         // basis: feature-pair 0..3 (feats 2fp,2fp+1)
    const int srow = tid >> 2;         // silu: row 0..127
    const int sq   = tid & 3;          // silu: 16-float quarter of the 64-k chunk

    f32x4 acc[4][4] = {};              // wave-tile 64x64
    bf16x8 bE[8], bO[8];               // B frag reg dbuf [nt*2+kkh]
    float4 xE[4], xO[4];               // x prefetch (depth 2); basis uses [0].xy

    // B fragment base: this lane's 16B within each 1KB fragment-block
    const unsigned short* wbase = WcF + (size_t)lane * 8;

    auto load_b = [&](int kc, bf16x8* dst) {
#pragma unroll
        for (int nt = 0; nt < 4; ++nt)
#pragma unroll
            for (int kkh = 0; kkh < 2; ++kkh)
                dst[nt * 2 + kkh] = *reinterpret_cast<const bf16x8*>(
                    wbase + ((size_t)((kc * 2 + kkh) * 16 + wn * 4 + nt)) * 512);
    };
    auto load_x = [&](int c, float4* xs) {
        if (c < 4) {
            const float* xp = x + (size_t)(row0 + srow) * IN_F + c * 64 + sq * 16;
            xs[0] = reinterpret_cast<const float4*>(xp)[0];
            xs[1] = reinterpret_cast<const float4*>(xp)[1];
            xs[2] = reinterpret_cast<const float4*>(xp)[2];
            xs[3] = reinterpret_cast<const float4*>(xp)[3];
        } else {
            const float* xp = x + (size_t)(row0 + erow) * IN_F + (c - 4) * 8 + efp * 2;
            float2 v = *reinterpret_cast<const float2*>(xp);
            xs[0].x = v.x; xs[0].y = v.y;
        }
    };
    // consume x(c) (loaded 1 chunk ago): silu -> VALU pack; basis -> table gathers
    auto expand = [&](int c, const float4* xs, uint4& w0, uint4& w1) {
        if (c < 4) {
            w0.x = f2bf(silu_f(xs[0].x)) | (f2bf(silu_f(xs[0].y)) << 16);
            w0.y = f2bf(silu_f(xs[0].z)) | (f2bf(silu_f(xs[0].w)) << 16);
            w0.z = f2bf(silu_f(xs[1].x)) | (f2bf(silu_f(xs[1].y)) << 16);
            w0.w = f2bf(silu_f(xs[1].z)) | (f2bf(silu_f(xs[1].w)) << 16);
            w1.x = f2bf(silu_f(xs[2].x)) | (f2bf(silu_f(xs[2].y)) << 16);
            w1.y = f2bf(silu_f(xs[2].z)) | (f2bf(silu_f(xs[2].w)) << 16);
            w1.z = f2bf(silu_f(xs[3].x)) | (f2bf(silu_f(xs[3].y)) << 16);
            w1.w = f2bf(silu_f(xs[3].z)) | (f2bf(silu_f(xs[3].w)) << 16);
        } else {
            float u0 = __builtin_fmaf(xs[0].x, 2.5f, 5.5f);
            float u1 = __builtin_fmaf(xs[0].y, 2.5f, 5.5f);
            int i0 = (int)floorf(u0 * (float)TBINS);
            int i1 = (int)floorf(u1 * (float)TBINS);
            i0 = i0 < -1 ? -1 : (i0 > NTAB ? NTAB : i0);
            i1 = i1 < -1 ? -1 : (i1 > NTAB ? NTAB : i1);
            w0 = tgt[i0 + 1];          // pre-positioned bf16x8 rows
            w1 = tgt[i1 + 1];
        }
    };
    auto write_a = [&](int c, int buf, const uint4& w0, const uint4& w1) {
        if (c < 4) {
            const int g0 = sq * 2;
            *reinterpret_cast<uint4*>(&As[buf][srow * 64 + ((g0 ^ (srow & 7)) << 3)]) = w0;
            *reinterpret_cast<uint4*>(&As[buf][srow * 64 + (((g0 + 1) ^ (srow & 7)) << 3)]) = w1;
        } else {
            const int g0 = efp * 2;
            *reinterpret_cast<uint4*>(&As[buf][erow * 64 + ((g0 ^ (erow & 7)) << 3)]) = w0;
            *reinterpret_cast<uint4*>(&As[buf][erow * 64 + (((g0 + 1) ^ (erow & 7)) << 3)]) = w1;
        }
    };
    auto mfma_chunk = [&](int cur, const bf16x8* bv) {
        bf16x8 af[2][4];
#pragma unroll
        for (int kkh = 0; kkh < 2; ++kkh) {
            const int g0 = kkh * 4 + q;
#pragma unroll
            for (int mt = 0; mt < 4; ++mt) {
                int r = wm * 64 + mt * 16 + l15;
                af[kkh][mt] = *reinterpret_cast<const bf16x8*>(
                    &As[cur][r * 64 + ((g0 ^ (r & 7)) << 3)]);
            }
        }
        __builtin_amdgcn_s_setprio(1);
#pragma unroll
        for (int kkh = 0; kkh < 2; ++kkh)
#pragma unroll
            for (int mt = 0; mt < 4; ++mt)
#pragma unroll
                for (int nt = 0; nt < 4; ++nt)
                    acc[mt][nt] = __builtin_amdgcn_mfma_f32_16x16x32_bf16(
                        af[kkh][mt], bv[nt * 2 + kkh], acc[mt][nt], 0, 0, 0);
        __builtin_amdgcn_s_setprio(0);
    };

    // prologue: x(0)->xE, x(1)->xO, B(0)->bE, expand+write A(0)
    load_x(0, xE);
    load_x(1, xO);
    load_b(0, bE);
    {
        uint4 wa, wb;
        expand(0, xE, wa, wb);
        write_a(0, 0, wa, wb);
    }
    __syncthreads();

    // steady state, parity-unrolled x2 (static reg-set naming).
    // per chunk kc: issue x(kc+2); expand(kc+1) [gathers from x loaded 1 chunk
    // ago]; issue B(kc+1) LAST so the pre-ds_write wait is a counted vmcnt;
    // MFMA(kc); ds_write A(kc+1); barrier.
    for (int kc = 0; kc < NCHUNK; kc += 2) {
        {   // even chunk kc: A buf0, bE
            uint4 wa, wb;
            if (kc + 2 < NCHUNK) load_x(kc + 2, xE);
            if (kc + 1 < NCHUNK) expand(kc + 1, xO, wa, wb);
            if (kc + 1 < NCHUNK) load_b(kc + 1, bO);
            mfma_chunk(0, bE);
            if (kc + 1 < NCHUNK) write_a(kc + 1, 1, wa, wb);
            __syncthreads();
        }
        {   // odd chunk kc+1: A buf1, bO
            uint4 wa, wb;
            if (kc + 3 < NCHUNK) load_x(kc + 3, xO);
            if (kc + 2 < NCHUNK) expand(kc + 2, xE, wa, wb);
            if (kc + 2 < NCHUNK) load_b(kc + 2, bE);
            mfma_chunk(1, bO);
            if (kc + 2 < NCHUNK) write_a(kc + 2, 0, wa, wb);
            __syncthreads();
        }
    }

    // epilogue: C/D layout col = lane&15, row = (lane>>4)*4 + reg
#pragma unroll
    for (int mt = 0; mt < 4; ++mt) {
        int row = row0 + wm * 64 + mt * 16 + q * 4;
#pragma unroll
        for (int nt = 0; nt < 4; ++nt) {
            int col = wn * 64 + nt * 16 + l15;
#pragma unroll
            for (int r = 0; r < 4; ++r)
                out[(size_t)(row + r) * OUT_F + col] = acc[mt][nt][r];
        }
    }
}

extern "C" void kernel_launch(void* const* d_in, const int* in_sizes, int n_in,
                              void* d_out, int out_size, void* d_ws, size_t ws_size,
                              hipStream_t stream) {
    const float* x  = (const float*)d_in[0];
    const float* bw = (const float*)d_in[1];
    const float* sw = (const float*)d_in[2];
    const float* ss = (const float*)d_in[3];
    unsigned short* WcF = (unsigned short*)d_ws;                // 1.18 MB
    uint4* tgt = (uint4*)((char*)d_ws + WC_BYTES);              // 90 KB table

    build_w<<<dim3(OUT_F), dim3(IN_F), 0, stream>>>(bw, sw, ss, WcF, tgt);

    const int B_ROWS = in_sizes[0] / IN_F;                      // 32768
    kan_fused<<<dim3(B_ROWS / 128), dim3(512), 0, stream>>>(
        x, WcF, tgt, (float*)d_out);
}

// Round 7
// 140.136 us; speedup vs baseline: 1.7117x; 1.1110x over previous
//
#include <hip/hip_runtime.h>
#include <stdint.h>

// KANLinear fused MFMA GEMM, R11 (resubmit; prior bench was an infra failure).
//   Cross-round invariant: MfmaUtil*dur ~= 15.3us every round => MFMA pipe time
//   is at its floor; dur is exposed VMEM-request time. R10's 2560 req/chunk/CU
//   (1024 table-gather + 512 basis-x + 1024 B lines) >> 1020cyc MFMA. Fix:
//   - basis coefs computed in VALU (~55 ops/elem, 440cyc/chunk/SIMD, overlaps
//     MFMA pipe) with packed-dword select positioning. More accurate than table.
//   - basis-x reads coalesced: thread(row=tid>>2,quad=tid&3) float2; 4 lanes
//     share a line -> ~128 lines/chunk (was ~1536 divergent).
//   - B direct L2->regs one chunk ahead, fragment-native Wc layout (R10, kept).
//   128x256 tile, 512 thr / 8 waves (2x4), wave-tile 64x64, grid 256 (1 blk/CU).
//   C = A @ W^T, A (B x 2304) = [silu(x) | bases(x)], W (256 x 2304) bf16 in ws.

#define IN_F 256
#define OUT_F 256
#define KDIM 2304 /* 256 silu + 256*8 basis */
#define BK 64
#define NCHUNK (KDIM / BK) /* 36, even */

typedef float f32x4 __attribute__((ext_vector_type(4)));
typedef short bf16x8 __attribute__((ext_vector_type(8)));

__device__ __forceinline__ uint32_t f2bf(float f) {
    union { float f; uint32_t u; } c; c.f = f;
    uint32_t u = c.u;
    return (u + 0x7FFFu + ((u >> 16) & 1u)) >> 16;   // RNE
}

__device__ __forceinline__ float silu_f(float v) {
    return v / (1.0f + __expf(-v));
}

// cubic B-spline: 16B fragment (8 bf16 coef slots) for one (row, feat) element.
// slot c (0..7) = p[c - (j0-3)] for c in [j0-3, j0], else 0; all-zero if j0
// outside [0,10]. Positioning via packed-dword selects (no shift/gather).
__device__ __forceinline__ uint4 basis16(float xx) {
    float u = __builtin_fmaf(xx, 2.5f, 5.5f);   // (x - grid0)/h
    float jf = floorf(u);
    float t = u - jf;
    int j0 = (int)jf;
    float t2 = t * t, t3 = t2 * t;
    float p3 = t3 * (1.0f / 6.0f);
    float p2 = __builtin_fmaf(t3, -0.5f,
               __builtin_fmaf(t2, 0.5f, __builtin_fmaf(t, 0.5f, 1.0f / 6.0f)));
    float p1 = __builtin_fmaf(t3, 0.5f, __builtin_fmaf(t2, -1.0f, 2.0f / 3.0f));
    float omt = 1.0f - t;
    float p0 = omt * omt * omt * (1.0f / 6.0f);
    uint32_t b0 = f2bf(p0), b1 = f2bf(p1), b2 = f2bf(p2), b3 = f2bf(p3);
    const int s0 = j0 - 3;
    int ds = s0 >> 1;                            // arithmetic: floor-div ok
    if ((unsigned)j0 > 10u) ds = 9;              // out of grid -> no dword match
    const bool odd = (s0 & 1) != 0;
    uint32_t v0 = odd ? (b0 << 16) : (b0 | (b1 << 16));
    uint32_t v1 = odd ? (b1 | (b2 << 16)) : (b2 | (b3 << 16));
    uint32_t v2 = odd ? b3 : 0u;
    uint4 r;
    r.x = (ds == 0) ? v0 : (ds == -1) ? v1 : (ds == -2) ? v2 : 0u;
    r.y = (ds == 1) ? v0 : (ds ==  0) ? v1 : (ds == -1) ? v2 : 0u;
    r.z = (ds == 2) ? v0 : (ds ==  1) ? v1 : (ds ==  0) ? v2 : 0u;
    r.w = (ds == 3) ? v0 : (ds ==  2) ? v1 : (ds ==  1) ? v2 : 0u;
    return r;
}

// fragment-native Wc address (in bf16 units) for element
//   W[col][kc*64 + kkh*32 + q*8 + e],  col = c16*16 + l15:
//   ((kc*2+kkh)*16 + c16)*512 + (q*16 + l15)*8 + e
__device__ __forceinline__ size_t wcf_addr(int col, int k) {
    const int kc = k >> 6, kkh = (k >> 5) & 1, q = (k >> 3) & 3, e = k & 7;
    return ((size_t)((kc * 2 + kkh) * 16 + (col >> 4))) * 512 +
           (size_t)(q * 16 + (col & 15)) * 8 + e;
}

// ---------------- kernel 1: fragment-native bf16 weight ----------------
__global__ void build_w(const float* __restrict__ bw, const float* __restrict__ sw,
                        const float* __restrict__ ss, unsigned short* __restrict__ WcF) {
    const int o = blockIdx.x;    // output col 0..255
    const int i = threadIdx.x;   // input feature 0..255
    WcF[wcf_addr(o, i)] = (unsigned short)f2bf(bw[o * IN_F + i]);
    const float scal = ss[o * IN_F + i];
    const float4* swv = reinterpret_cast<const float4*>(sw + (size_t)(o * IN_F + i) * 8);
    float4 s0 = swv[0], s1 = swv[1];
    uint4 wv;
    wv.x = f2bf(s0.x * scal) | (f2bf(s0.y * scal) << 16);
    wv.y = f2bf(s0.z * scal) | (f2bf(s0.w * scal) << 16);
    wv.z = f2bf(s1.x * scal) | (f2bf(s1.y * scal) << 16);
    wv.w = f2bf(s1.z * scal) | (f2bf(s1.w * scal) << 16);
    *reinterpret_cast<uint4*>(WcF + wcf_addr(o, IN_F + i * 8)) = wv;
}

// ---------------- kernel 2: fused GEMM, 512 threads ----------------
// A LDS layout per tile: addr(row, g) = row*128B + ((g ^ (row&7))*16B), g = k/8
__launch_bounds__(512, 2)
__global__ void kan_fused(const float* __restrict__ x, const unsigned short* __restrict__ WcF,
                          float* __restrict__ out) {
    __shared__ __align__(16) unsigned short As[2][128 * 64];   // 32 KB

    const int bid = blockIdx.x;
    const int row0 = bid * 128;
    const int tid = threadIdx.x;
    const int lane = tid & 63;
    const int w = tid >> 6;            // wave id 0..7
    const int wm = w >> 2;             // 0..1 : 64-row half
    const int wn = w & 3;              // 0..3 : 64-col quarter
    const int l15 = lane & 15;
    const int q = lane >> 4;

    // A-expansion mapping (each element exactly once, coalesced x reads):
    //   thread -> (row = tid>>2, qd = tid&3); owns k-segments {qd*2, qd*2+1}
    //   silu chunk  c<4 : x[row, c*64 + qd*16 .. +15]  (float4 x4, 1 line/4 lanes)
    //   basis chunk c>=4: x[row, (c-4)*8 + qd*2 .. +1] (float2, 1 line/4 lanes)
    const int erow = tid >> 2;         // 0..127
    const int qd   = tid & 3;          // 0..3

    f32x4 acc[4][4] = {};              // wave-tile 64x64
    bf16x8 bE[8], bO[8];               // B frag reg dbuf [nt*2+kkh]
    float4 xE[4], xO[4];               // x prefetch (depth 2); basis uses [0].xy

    // B fragment base: this lane's 16B within each 1KB fragment-block
    const unsigned short* wbase = WcF + (size_t)lane * 8;

    auto load_b = [&](int kc, bf16x8* dst) {
#pragma unroll
        for (int nt = 0; nt < 4; ++nt)
#pragma unroll
            for (int kkh = 0; kkh < 2; ++kkh)
                dst[nt * 2 + kkh] = *reinterpret_cast<const bf16x8*>(
                    wbase + ((size_t)((kc * 2 + kkh) * 16 + wn * 4 + nt)) * 512);
    };
    auto load_x = [&](int c, float4* xs) {
        if (c < 4) {
            const float* xp = x + (size_t)(row0 + erow) * IN_F + c * 64 + qd * 16;
            xs[0] = reinterpret_cast<const float4*>(xp)[0];
            xs[1] = reinterpret_cast<const float4*>(xp)[1];
            xs[2] = reinterpret_cast<const float4*>(xp)[2];
            xs[3] = reinterpret_cast<const float4*>(xp)[3];
        } else {
            const float* xp = x + (size_t)(row0 + erow) * IN_F + (c - 4) * 8 + qd * 2;
            float2 v = *reinterpret_cast<const float2*>(xp);
            xs[0].x = v.x; xs[0].y = v.y;
        }
    };
    // consume x(c) (loaded 2 chunks ago): silu VALU pack, or VALU basis eval
    auto expand = [&](int c, const float4* xs, uint4& w0, uint4& w1) {
        if (c < 4) {
            w0.x = f2bf(silu_f(xs[0].x)) | (f2bf(silu_f(xs[0].y)) << 16);
            w0.y = f2bf(silu_f(xs[0].z)) | (f2bf(silu_f(xs[0].w)) << 16);
            w0.z = f2bf(silu_f(xs[1].x)) | (f2bf(silu_f(xs[1].y)) << 16);
            w0.w = f2bf(silu_f(xs[1].z)) | (f2bf(silu_f(xs[1].w)) << 16);
            w1.x = f2bf(silu_f(xs[2].x)) | (f2bf(silu_f(xs[2].y)) << 16);
            w1.y = f2bf(silu_f(xs[2].z)) | (f2bf(silu_f(xs[2].w)) << 16);
            w1.z = f2bf(silu_f(xs[3].x)) | (f2bf(silu_f(xs[3].y)) << 16);
            w1.w = f2bf(silu_f(xs[3].z)) | (f2bf(silu_f(xs[3].w)) << 16);
        } else {
            w0 = basis16(xs[0].x);
            w1 = basis16(xs[0].y);
        }
    };
    auto write_a = [&](int buf, const uint4& w0, const uint4& w1) {
        const int g0 = qd * 2;
        *reinterpret_cast<uint4*>(&As[buf][erow * 64 + ((g0 ^ (erow & 7)) << 3)]) = w0;
        *reinterpret_cast<uint4*>(&As[buf][erow * 64 + (((g0 + 1) ^ (erow & 7)) << 3)]) = w1;
    };
    auto mfma_chunk = [&](int cur, const bf16x8* bv) {
        bf16x8 af[2][4];
#pragma unroll
        for (int kkh = 0; kkh < 2; ++kkh) {
            const int g0 = kkh * 4 + q;
#pragma unroll
            for (int mt = 0; mt < 4; ++mt) {
                int r = wm * 64 + mt * 16 + l15;
                af[kkh][mt] = *reinterpret_cast<const bf16x8*>(
                    &As[cur][r * 64 + ((g0 ^ (r & 7)) << 3)]);
            }
        }
        __builtin_amdgcn_s_setprio(1);
#pragma unroll
        for (int kkh = 0; kkh < 2; ++kkh)
#pragma unroll
            for (int mt = 0; mt < 4; ++mt)
#pragma unroll
                for (int nt = 0; nt < 4; ++nt)
                    acc[mt][nt] = __builtin_amdgcn_mfma_f32_16x16x32_bf16(
                        af[kkh][mt], bv[nt * 2 + kkh], acc[mt][nt], 0, 0, 0);
        __builtin_amdgcn_s_setprio(0);
    };

    // prologue: x(0)->xE, x(1)->xO, B(0)->bE, expand+write A(0)
    load_x(0, xE);
    load_x(1, xO);
    load_b(0, bE);
    {
        uint4 wa, wb;
        expand(0, xE, wa, wb);
        write_a(0, wa, wb);
    }
    __syncthreads();

    // steady state, parity-unrolled x2 (static reg-set naming).
    // per chunk kc: issue B(kc+1) + x(kc+2) first (loads in flight under VALU
    // + MFMA); expand(kc+1) in VALU; MFMA(kc); ds_write A(kc+1); barrier.
    for (int kc = 0; kc < NCHUNK; kc += 2) {
        {   // even chunk kc: A buf0, bE
            uint4 wa, wb;
            if (kc + 1 < NCHUNK) load_b(kc + 1, bO);
            if (kc + 2 < NCHUNK) load_x(kc + 2, xE);
            if (kc + 1 < NCHUNK) expand(kc + 1, xO, wa, wb);
            mfma_chunk(0, bE);
            if (kc + 1 < NCHUNK) write_a(1, wa, wb);
            __syncthreads();
        }
        {   // odd chunk kc+1: A buf1, bO
            uint4 wa, wb;
            if (kc + 2 < NCHUNK) load_b(kc + 2, bE);
            if (kc + 3 < NCHUNK) load_x(kc + 3, xO);
            if (kc + 2 < NCHUNK) expand(kc + 2, xE, wa, wb);
            mfma_chunk(1, bO);
            if (kc + 2 < NCHUNK) write_a(0, wa, wb);
            __syncthreads();
        }
    }

    // epilogue: C/D layout col = lane&15, row = (lane>>4)*4 + reg
#pragma unroll
    for (int mt = 0; mt < 4; ++mt) {
        int row = row0 + wm * 64 + mt * 16 + q * 4;
#pragma unroll
        for (int nt = 0; nt < 4; ++nt) {
            int col = wn * 64 + nt * 16 + l15;
#pragma unroll
            for (int r = 0; r < 4; ++r)
                out[(size_t)(row + r) * OUT_F + col] = acc[mt][nt][r];
        }
    }
}

extern "C" void kernel_launch(void* const* d_in, const int* in_sizes, int n_in,
                              void* d_out, int out_size, void* d_ws, size_t ws_size,
                              hipStream_t stream) {
    const float* x  = (const float*)d_in[0];
    const float* bw = (const float*)d_in[1];
    const float* sw = (const float*)d_in[2];
    const float* ss = (const float*)d_in[3];
    unsigned short* WcF = (unsigned short*)d_ws;                // 1.18 MB

    build_w<<<dim3(OUT_F), dim3(IN_F), 0, stream>>>(bw, sw, ss, WcF);

    const int B_ROWS = in_sizes[0] / IN_F;                      // 32768
    kan_fused<<<dim3(B_ROWS / 128), dim3(512), 0, stream>>>(
        x, WcF, (float*)d_out);
}

// Round 8
// 138.144 us; speedup vs baseline: 1.7364x; 1.0144x over previous
//
#include <hip/hip_runtime.h>
#include <stdint.h>

// KANLinear fused MFMA GEMM, R12: kill the barrier vmcnt-drain (T4, counted vmcnt).
//   R6-R11 invariant: every 2-barrier-per-chunk variant lands at ~573-607 TF eff
//   = the documented 2-phase structural ceiling (m233/m248); MfmaUtil*dur ~ 15us
//   (MFMA floor) regardless of phase content. The stall is __syncthreads()'s
//   forced s_waitcnt vmcnt(0) before s_barrier. Since R11 all VMEM results (B
//   frags, x) are same-wave-consumed, cross-wave visibility is only needed for
//   LDS (A tile) -> replace __syncthreads with {s_waitcnt lgkmcnt(0); s_barrier}
//   so B(kc+1)/x(kc+2) loads stay in flight across barriers and drain at their
//   compiler-counted use sites one chunk later (HK/m201 pattern).
//   Everything else identical to R11 (bit-identical numerics).
//   128x256 tile, 512 thr / 8 waves (2x4), wave-tile 64x64, grid 256 (1 blk/CU).
//   C = A @ W^T, A (B x 2304) = [silu(x) | bases(x)], W (256 x 2304) bf16 in ws.

#define IN_F 256
#define OUT_F 256
#define KDIM 2304 /* 256 silu + 256*8 basis */
#define BK 64
#define NCHUNK (KDIM / BK) /* 36, even */

typedef float f32x4 __attribute__((ext_vector_type(4)));
typedef short bf16x8 __attribute__((ext_vector_type(8)));

__device__ __forceinline__ uint32_t f2bf(float f) {
    union { float f; uint32_t u; } c; c.f = f;
    uint32_t u = c.u;
    return (u + 0x7FFFu + ((u >> 16) & 1u)) >> 16;   // RNE
}

__device__ __forceinline__ float silu_f(float v) {
    return v / (1.0f + __expf(-v));
}

// LDS-only block barrier: waits LDS ops (lgkmcnt) but leaves the VMEM queue
// (vmcnt) in flight across the barrier -- the whole point of R12.
__device__ __forceinline__ void block_sync_lds() {
    __builtin_amdgcn_sched_barrier(0);
    asm volatile("s_waitcnt lgkmcnt(0)" ::: "memory");
    __builtin_amdgcn_sched_barrier(0);
    __builtin_amdgcn_s_barrier();
    __builtin_amdgcn_sched_barrier(0);
}

// cubic B-spline: 16B fragment (8 bf16 coef slots) for one (row, feat) element.
// slot c (0..7) = p[c - (j0-3)] for c in [j0-3, j0], else 0; all-zero if j0
// outside [0,10]. Positioning via packed-dword selects (no shift/gather).
__device__ __forceinline__ uint4 basis16(float xx) {
    float u = __builtin_fmaf(xx, 2.5f, 5.5f);   // (x - grid0)/h
    float jf = floorf(u);
    float t = u - jf;
    int j0 = (int)jf;
    float t2 = t * t, t3 = t2 * t;
    float p3 = t3 * (1.0f / 6.0f);
    float p2 = __builtin_fmaf(t3, -0.5f,
               __builtin_fmaf(t2, 0.5f, __builtin_fmaf(t, 0.5f, 1.0f / 6.0f)));
    float p1 = __builtin_fmaf(t3, 0.5f, __builtin_fmaf(t2, -1.0f, 2.0f / 3.0f));
    float omt = 1.0f - t;
    float p0 = omt * omt * omt * (1.0f / 6.0f);
    uint32_t b0 = f2bf(p0), b1 = f2bf(p1), b2 = f2bf(p2), b3 = f2bf(p3);
    const int s0 = j0 - 3;
    int ds = s0 >> 1;                            // arithmetic: floor-div ok
    if ((unsigned)j0 > 10u) ds = 9;              // out of grid -> no dword match
    const bool odd = (s0 & 1) != 0;
    uint32_t v0 = odd ? (b0 << 16) : (b0 | (b1 << 16));
    uint32_t v1 = odd ? (b1 | (b2 << 16)) : (b2 | (b3 << 16));
    uint32_t v2 = odd ? b3 : 0u;
    uint4 r;
    r.x = (ds == 0) ? v0 : (ds == -1) ? v1 : (ds == -2) ? v2 : 0u;
    r.y = (ds == 1) ? v0 : (ds ==  0) ? v1 : (ds == -1) ? v2 : 0u;
    r.z = (ds == 2) ? v0 : (ds ==  1) ? v1 : (ds ==  0) ? v2 : 0u;
    r.w = (ds == 3) ? v0 : (ds ==  2) ? v1 : (ds ==  1) ? v2 : 0u;
    return r;
}

// fragment-native Wc address (in bf16 units) for element
//   W[col][kc*64 + kkh*32 + q*8 + e],  col = c16*16 + l15:
//   ((kc*2+kkh)*16 + c16)*512 + (q*16 + l15)*8 + e
__device__ __forceinline__ size_t wcf_addr(int col, int k) {
    const int kc = k >> 6, kkh = (k >> 5) & 1, q = (k >> 3) & 3, e = k & 7;
    return ((size_t)((kc * 2 + kkh) * 16 + (col >> 4))) * 512 +
           (size_t)(q * 16 + (col & 15)) * 8 + e;
}

// ---------------- kernel 1: fragment-native bf16 weight ----------------
__global__ void build_w(const float* __restrict__ bw, const float* __restrict__ sw,
                        const float* __restrict__ ss, unsigned short* __restrict__ WcF) {
    const int o = blockIdx.x;    // output col 0..255
    const int i = threadIdx.x;   // input feature 0..255
    WcF[wcf_addr(o, i)] = (unsigned short)f2bf(bw[o * IN_F + i]);
    const float scal = ss[o * IN_F + i];
    const float4* swv = reinterpret_cast<const float4*>(sw + (size_t)(o * IN_F + i) * 8);
    float4 s0 = swv[0], s1 = swv[1];
    uint4 wv;
    wv.x = f2bf(s0.x * scal) | (f2bf(s0.y * scal) << 16);
    wv.y = f2bf(s0.z * scal) | (f2bf(s0.w * scal) << 16);
    wv.z = f2bf(s1.x * scal) | (f2bf(s1.y * scal) << 16);
    wv.w = f2bf(s1.z * scal) | (f2bf(s1.w * scal) << 16);
    *reinterpret_cast<uint4*>(WcF + wcf_addr(o, IN_F + i * 8)) = wv;
}

// ---------------- kernel 2: fused GEMM, 512 threads ----------------
// A LDS layout per tile: addr(row, g) = row*128B + ((g ^ (row&7))*16B), g = k/8
__launch_bounds__(512, 2)
__global__ void kan_fused(const float* __restrict__ x, const unsigned short* __restrict__ WcF,
                          float* __restrict__ out) {
    __shared__ __align__(16) unsigned short As[2][128 * 64];   // 32 KB

    const int bid = blockIdx.x;
    const int row0 = bid * 128;
    const int tid = threadIdx.x;
    const int lane = tid & 63;
    const int w = tid >> 6;            // wave id 0..7
    const int wm = w >> 2;             // 0..1 : 64-row half
    const int wn = w & 3;              // 0..3 : 64-col quarter
    const int l15 = lane & 15;
    const int q = lane >> 4;

    // A-expansion mapping (each element exactly once, coalesced x reads):
    //   thread -> (row = tid>>2, qd = tid&3); owns k-segments {qd*2, qd*2+1}
    //   silu chunk  c<4 : x[row, c*64 + qd*16 .. +15]  (float4 x4, 1 line/4 lanes)
    //   basis chunk c>=4: x[row, (c-4)*8 + qd*2 .. +1] (float2, 1 line/4 lanes)
    const int erow = tid >> 2;         // 0..127
    const int qd   = tid & 3;          // 0..3

    f32x4 acc[4][4] = {};              // wave-tile 64x64
    bf16x8 bE[8], bO[8];               // B frag reg dbuf [nt*2+kkh]
    float4 xE[4], xO[4];               // x prefetch (depth 2); basis uses [0].xy

    // B fragment base: this lane's 16B within each 1KB fragment-block
    const unsigned short* wbase = WcF + (size_t)lane * 8;

    auto load_b = [&](int kc, bf16x8* dst) {
#pragma unroll
        for (int nt = 0; nt < 4; ++nt)
#pragma unroll
            for (int kkh = 0; kkh < 2; ++kkh)
                dst[nt * 2 + kkh] = *reinterpret_cast<const bf16x8*>(
                    wbase + ((size_t)((kc * 2 + kkh) * 16 + wn * 4 + nt)) * 512);
    };
    auto load_x = [&](int c, float4* xs) {
        if (c < 4) {
            const float* xp = x + (size_t)(row0 + erow) * IN_F + c * 64 + qd * 16;
            xs[0] = reinterpret_cast<const float4*>(xp)[0];
            xs[1] = reinterpret_cast<const float4*>(xp)[1];
            xs[2] = reinterpret_cast<const float4*>(xp)[2];
            xs[3] = reinterpret_cast<const float4*>(xp)[3];
        } else {
            const float* xp = x + (size_t)(row0 + erow) * IN_F + (c - 4) * 8 + qd * 2;
            float2 v = *reinterpret_cast<const float2*>(xp);
            xs[0].x = v.x; xs[0].y = v.y;
        }
    };
    // consume x(c) (loaded 2 chunks ago): silu VALU pack, or VALU basis eval
    auto expand = [&](int c, const float4* xs, uint4& w0, uint4& w1) {
        if (c < 4) {
            w0.x = f2bf(silu_f(xs[0].x)) | (f2bf(silu_f(xs[0].y)) << 16);
            w0.y = f2bf(silu_f(xs[0].z)) | (f2bf(silu_f(xs[0].w)) << 16);
            w0.z = f2bf(silu_f(xs[1].x)) | (f2bf(silu_f(xs[1].y)) << 16);
            w0.w = f2bf(silu_f(xs[1].z)) | (f2bf(silu_f(xs[1].w)) << 16);
            w1.x = f2bf(silu_f(xs[2].x)) | (f2bf(silu_f(xs[2].y)) << 16);
            w1.y = f2bf(silu_f(xs[2].z)) | (f2bf(silu_f(xs[2].w)) << 16);
            w1.z = f2bf(silu_f(xs[3].x)) | (f2bf(silu_f(xs[3].y)) << 16);
            w1.w = f2bf(silu_f(xs[3].z)) | (f2bf(silu_f(xs[3].w)) << 16);
        } else {
            w0 = basis16(xs[0].x);
            w1 = basis16(xs[0].y);
        }
    };
    auto write_a = [&](int buf, const uint4& w0, const uint4& w1) {
        const int g0 = qd * 2;
        *reinterpret_cast<uint4*>(&As[buf][erow * 64 + ((g0 ^ (erow & 7)) << 3)]) = w0;
        *reinterpret_cast<uint4*>(&As[buf][erow * 64 + (((g0 + 1) ^ (erow & 7)) << 3)]) = w1;
    };
    auto mfma_chunk = [&](int cur, const bf16x8* bv) {
        bf16x8 af[2][4];
#pragma unroll
        for (int kkh = 0; kkh < 2; ++kkh) {
            const int g0 = kkh * 4 + q;
#pragma unroll
            for (int mt = 0; mt < 4; ++mt) {
                int r = wm * 64 + mt * 16 + l15;
                af[kkh][mt] = *reinterpret_cast<const bf16x8*>(
                    &As[cur][r * 64 + ((g0 ^ (r & 7)) << 3)]);
            }
        }
        __builtin_amdgcn_s_setprio(1);
#pragma unroll
        for (int kkh = 0; kkh < 2; ++kkh)
#pragma unroll
            for (int mt = 0; mt < 4; ++mt)
#pragma unroll
                for (int nt = 0; nt < 4; ++nt)
                    acc[mt][nt] = __builtin_amdgcn_mfma_f32_16x16x32_bf16(
                        af[kkh][mt], bv[nt * 2 + kkh], acc[mt][nt], 0, 0, 0);
        __builtin_amdgcn_s_setprio(0);
    };

    // prologue: x(0)->xE, x(1)->xO, B(0)->bE, expand+write A(0)
    load_x(0, xE);
    load_x(1, xO);
    load_b(0, bE);
    {
        uint4 wa, wb;
        expand(0, xE, wa, wb);
        write_a(0, wa, wb);
    }
    block_sync_lds();

    // steady state, parity-unrolled x2 (static reg-set naming).
    // per chunk kc: issue B(kc+1) + x(kc+2) first (stay in flight ACROSS the
    // barrier now); expand(kc+1) in VALU; MFMA(kc); ds_write A(kc+1);
    // lgkm-only barrier.
    for (int kc = 0; kc < NCHUNK; kc += 2) {
        {   // even chunk kc: A buf0, bE
            uint4 wa, wb;
            if (kc + 1 < NCHUNK) load_b(kc + 1, bO);
            if (kc + 2 < NCHUNK) load_x(kc + 2, xE);
            if (kc + 1 < NCHUNK) expand(kc + 1, xO, wa, wb);
            mfma_chunk(0, bE);
            if (kc + 1 < NCHUNK) write_a(1, wa, wb);
            block_sync_lds();
        }
        {   // odd chunk kc+1: A buf1, bO
            uint4 wa, wb;
            if (kc + 2 < NCHUNK) load_b(kc + 2, bE);
            if (kc + 3 < NCHUNK) load_x(kc + 3, xO);
            if (kc + 2 < NCHUNK) expand(kc + 2, xE, wa, wb);
            mfma_chunk(1, bO);
            if (kc + 2 < NCHUNK) write_a(0, wa, wb);
            block_sync_lds();
        }
    }

    // epilogue: C/D layout col = lane&15, row = (lane>>4)*4 + reg
#pragma unroll
    for (int mt = 0; mt < 4; ++mt) {
        int row = row0 + wm * 64 + mt * 16 + q * 4;
#pragma unroll
        for (int nt = 0; nt < 4; ++nt) {
            int col = wn * 64 + nt * 16 + l15;
#pragma unroll
            for (int r = 0; r < 4; ++r)
                out[(size_t)(row + r) * OUT_F + col] = acc[mt][nt][r];
        }
    }
}

extern "C" void kernel_launch(void* const* d_in, const int* in_sizes, int n_in,
                              void* d_out, int out_size, void* d_ws, size_t ws_size,
                              hipStream_t stream) {
    const float* x  = (const float*)d_in[0];
    const float* bw = (const float*)d_in[1];
    const float* sw = (const float*)d_in[2];
    const float* ss = (const float*)d_in[3];
    unsigned short* WcF = (unsigned short*)d_ws;                // 1.18 MB

    build_w<<<dim3(OUT_F), dim3(IN_F), 0, stream>>>(bw, sw, ss, WcF);

    const int B_ROWS = in_sizes[0] / IN_F;                      // 32768
    kan_fused<<<dim3(B_ROWS / 128), dim3(512), 0, stream>>>(
        x, WcF, (float*)d_out);
}

// Round 9
// 137.082 us; speedup vs baseline: 1.7499x; 1.0077x over previous
//
#include <hip/hip_runtime.h>
#include <stdint.h>

// KANLinear fused MFMA GEMM, R13: de-convoy the chunk loop.
//   Invariant across R6-R12: every design delivers 128 KB/chunk/CU of MFMA
//   operands (A 64 + B 64, wave-tile-optimal) in post-barrier bursts -> chunk
//   wall ~4400 cyc vs 1090 MFMA. Fix the *schedule*, not the traffic:
//   - superstep-2: barrier per 2 chunks (18 barriers), 4 A-buffers (64 KB LDS)
//   - wave stagger: waves 0-3 {expand->mfma}, 4-7 {mfma->expand} -> VALU/MFMA
//     anti-phase on each SIMD (one wave of each group per SIMD)
//   - af ds_read interleaved per-mt into the MFMA stream
//   - v_cvt_pk_bf16_f32 packing (-25% expand VALU)
//   128x256 tile, 512 thr / 8 waves (2x4), wave-tile 64x64, grid 256 (1 blk/CU).
//   C = A @ W^T, A (B x 2304) = [silu(x) | bases(x)], W (256 x 2304) bf16 in ws.

#define IN_F 256
#define OUT_F 256
#define KDIM 2304 /* 256 silu + 256*8 basis */
#define BK 64
#define NCHUNK (KDIM / BK) /* 36 */

typedef float f32x4 __attribute__((ext_vector_type(4)));
typedef short bf16x8 __attribute__((ext_vector_type(8)));

__device__ __forceinline__ uint32_t f2bf(float f) {
    union { float f; uint32_t u; } c; c.f = f;
    uint32_t u = c.u;
    return (u + 0x7FFFu + ((u >> 16) & 1u)) >> 16;   // RNE
}

__device__ __forceinline__ uint32_t cvtpk(float lo, float hi) {
    uint32_t r;
    asm("v_cvt_pk_bf16_f32 %0, %1, %2" : "=v"(r) : "v"(lo), "v"(hi));
    return r;
}

__device__ __forceinline__ float silu_f(float v) {
    return v / (1.0f + __expf(-v));
}

// LDS-only block barrier: waits LDS ops but leaves the VMEM queue in flight.
__device__ __forceinline__ void block_sync_lds() {
    __builtin_amdgcn_sched_barrier(0);
    asm volatile("s_waitcnt lgkmcnt(0)" ::: "memory");
    __builtin_amdgcn_sched_barrier(0);
    __builtin_amdgcn_s_barrier();
    __builtin_amdgcn_sched_barrier(0);
}

// cubic B-spline: 16B fragment (8 bf16 coef slots) for one (row, feat) element.
__device__ __forceinline__ uint4 basis16(float xx) {
    float u = __builtin_fmaf(xx, 2.5f, 5.5f);   // (x - grid0)/h
    float jf = floorf(u);
    float t = u - jf;
    int j0 = (int)jf;
    float t2 = t * t, t3 = t2 * t;
    float p3 = t3 * (1.0f / 6.0f);
    float p2 = __builtin_fmaf(t3, -0.5f,
               __builtin_fmaf(t2, 0.5f, __builtin_fmaf(t, 0.5f, 1.0f / 6.0f)));
    float p1 = __builtin_fmaf(t3, 0.5f, __builtin_fmaf(t2, -1.0f, 2.0f / 3.0f));
    float omt = 1.0f - t;
    float p0 = omt * omt * omt * (1.0f / 6.0f);
    const int s0 = j0 - 3;
    int ds = s0 >> 1;                            // arithmetic: floor-div ok
    if ((unsigned)j0 > 10u) ds = 9;              // out of grid -> no dword match
    const bool odd = (s0 & 1) != 0;
    uint32_t v0 = cvtpk(odd ? 0.0f : p0, odd ? p0 : p1);
    uint32_t v1 = cvtpk(odd ? p1 : p2, odd ? p2 : p3);
    uint32_t v2 = odd ? cvtpk(p3, 0.0f) : 0u;
    uint4 r;
    r.x = (ds == 0) ? v0 : (ds == -1) ? v1 : (ds == -2) ? v2 : 0u;
    r.y = (ds == 1) ? v0 : (ds ==  0) ? v1 : (ds == -1) ? v2 : 0u;
    r.z = (ds == 2) ? v0 : (ds ==  1) ? v1 : (ds ==  0) ? v2 : 0u;
    r.w = (ds == 3) ? v0 : (ds ==  2) ? v1 : (ds ==  1) ? v2 : 0u;
    return r;
}

// fragment-native Wc address (bf16 units): W[col][kc*64+kkh*32+q*8+e]
__device__ __forceinline__ size_t wcf_addr(int col, int k) {
    const int kc = k >> 6, kkh = (k >> 5) & 1, q = (k >> 3) & 3, e = k & 7;
    return ((size_t)((kc * 2 + kkh) * 16 + (col >> 4))) * 512 +
           (size_t)(q * 16 + (col & 15)) * 8 + e;
}

// ---------------- kernel 1: fragment-native bf16 weight ----------------
__global__ void build_w(const float* __restrict__ bw, const float* __restrict__ sw,
                        const float* __restrict__ ss, unsigned short* __restrict__ WcF) {
    const int o = blockIdx.x;    // output col 0..255
    const int i = threadIdx.x;   // input feature 0..255
    WcF[wcf_addr(o, i)] = (unsigned short)f2bf(bw[o * IN_F + i]);
    const float scal = ss[o * IN_F + i];
    const float4* swv = reinterpret_cast<const float4*>(sw + (size_t)(o * IN_F + i) * 8);
    float4 s0 = swv[0], s1 = swv[1];
    uint4 wv;
    wv.x = f2bf(s0.x * scal) | (f2bf(s0.y * scal) << 16);
    wv.y = f2bf(s0.z * scal) | (f2bf(s0.w * scal) << 16);
    wv.z = f2bf(s1.x * scal) | (f2bf(s1.y * scal) << 16);
    wv.w = f2bf(s1.z * scal) | (f2bf(s1.w * scal) << 16);
    *reinterpret_cast<uint4*>(WcF + wcf_addr(o, IN_F + i * 8)) = wv;
}

// ---------------- kernel 2: fused GEMM, 512 threads ----------------
// A LDS layout per buffer: addr(row, g) = row*128B + ((g ^ (row&7))*16B)
__launch_bounds__(512, 2)
__global__ void kan_fused(const float* __restrict__ x, const unsigned short* __restrict__ WcF,
                          float* __restrict__ out) {
    __shared__ __align__(16) unsigned short As[4][128 * 64];   // 64 KB

    const int bid = blockIdx.x;
    const int row0 = bid * 128;
    const int tid = threadIdx.x;
    const int lane = tid & 63;
    const int w = tid >> 6;            // wave id 0..7
    const int wm = w >> 2;             // 0..1 : 64-row half
    const int wn = w & 3;              // 0..3 : 64-col quarter
    const int l15 = lane & 15;
    const int q = lane >> 4;

    // A-expansion mapping (each element once, coalesced x reads):
    const int erow = tid >> 2;         // 0..127
    const int qd   = tid & 3;          // 0..3

    f32x4 acc[4][4] = {};              // wave-tile 64x64
    bf16x8 bE[8], bO[8];               // B frag reg dbuf [nt*2+kkh]
    float2 x0, x1, x2, x3;             // basis x sets (set = chunk & 3)

    const unsigned short* wbase = WcF + (size_t)lane * 8;

    auto load_b = [&](int kc, bf16x8* dst) {
#pragma unroll
        for (int nt = 0; nt < 4; ++nt)
#pragma unroll
            for (int kkh = 0; kkh < 2; ++kkh)
                dst[nt * 2 + kkh] = *reinterpret_cast<const bf16x8*>(
                    wbase + ((size_t)((kc * 2 + kkh) * 16 + wn * 4 + nt)) * 512);
    };
    auto load_x_silu = [&](int c, float4* xs4) {
        const float* xp = x + (size_t)(row0 + erow) * IN_F + c * 64 + qd * 16;
#pragma unroll
        for (int i = 0; i < 4; ++i)
            xs4[i] = reinterpret_cast<const float4*>(xp)[i];
    };
    auto load_x_bas = [&](int c, float2& v) {
        v = *reinterpret_cast<const float2*>(
            x + (size_t)(row0 + erow) * IN_F + (c - 4) * 8 + qd * 2);
    };
    auto expand_silu = [&](const float4* xs4, uint4& w0, uint4& w1) {
        w0.x = cvtpk(silu_f(xs4[0].x), silu_f(xs4[0].y));
        w0.y = cvtpk(silu_f(xs4[0].z), silu_f(xs4[0].w));
        w0.z = cvtpk(silu_f(xs4[1].x), silu_f(xs4[1].y));
        w0.w = cvtpk(silu_f(xs4[1].z), silu_f(xs4[1].w));
        w1.x = cvtpk(silu_f(xs4[2].x), silu_f(xs4[2].y));
        w1.y = cvtpk(silu_f(xs4[2].z), silu_f(xs4[2].w));
        w1.z = cvtpk(silu_f(xs4[3].x), silu_f(xs4[3].y));
        w1.w = cvtpk(silu_f(xs4[3].z), silu_f(xs4[3].w));
    };
    auto expand_bas = [&](float2 v, uint4& w0, uint4& w1) {
        w0 = basis16(v.x);
        w1 = basis16(v.y);
    };
    auto write_a = [&](unsigned short* Ab, const uint4& w0, const uint4& w1) {
        const int g0 = qd * 2;
        *reinterpret_cast<uint4*>(Ab + erow * 64 + ((g0 ^ (erow & 7)) << 3)) = w0;
        *reinterpret_cast<uint4*>(Ab + erow * 64 + (((g0 + 1) ^ (erow & 7)) << 3)) = w1;
    };
    // af reads interleaved per-mt into the MFMA stream
    auto mfma_chunk = [&](const unsigned short* Ab, const bf16x8* bv) {
#pragma unroll
        for (int kkh = 0; kkh < 2; ++kkh) {
            const int g0 = kkh * 4 + q;
#pragma unroll
            for (int mt = 0; mt < 4; ++mt) {
                int r = wm * 64 + mt * 16 + l15;
                bf16x8 a = *reinterpret_cast<const bf16x8*>(
                    Ab + r * 64 + ((g0 ^ (r & 7)) << 3));
                __builtin_amdgcn_s_setprio(1);
#pragma unroll
                for (int nt = 0; nt < 4; ++nt)
                    acc[mt][nt] = __builtin_amdgcn_mfma_f32_16x16x32_bf16(
                        a, bv[nt * 2 + kkh], acc[mt][nt], 0, 0, 0);
                __builtin_amdgcn_s_setprio(0);
            }
        }
    };

    // ---- prologue: chunks 0,1 expanded+written; x(2..5) in flight; B(0) ----
    float4 xf2[4], xf3[4];             // silu x for chunks 2,3 (live thru SS0)
    {
        float4 t4[4]; uint4 a, b;
        load_x_silu(0, t4); expand_silu(t4, a, b); write_a(&As[0][0], a, b);
        load_x_silu(1, t4); expand_silu(t4, a, b); write_a(&As[1][0], a, b);
    }
    load_x_silu(2, xf2);
    load_x_silu(3, xf3);
    load_x_bas(4, x0);
    load_x_bas(5, x1);
    load_b(0, bE);
    block_sync_lds();

    // ---- superstep 0 (special: silu expansion of chunks 2,3) ----
    load_b(1, bO);
    load_x_bas(6, x2);
    load_x_bas(7, x3);
    {
        uint4 a2, b2, a3, b3;
        expand_silu(xf2, a2, b2); expand_silu(xf3, a3, b3);
        write_a(&As[2][0], a2, b2); write_a(&As[3][0], a3, b3);
    }
    mfma_chunk(&As[0][0], bE);
    load_b(2, bE);
    mfma_chunk(&As[1][0], bO);
    block_sync_lds();

    // ---- supersteps 1..16 (basis region), pairs {odd s, even s} ----
    for (int t = 0; t < 8; ++t) {
        {   // odd superstep: chunks kc,kc+1 = 4t+2,4t+3; read bufs 2,3; write 0,1
            const int kc = 4 * t + 2;
            load_b(kc + 1, bO);
            load_x_bas(kc + 4, x2);        // chunks 4t+6,4t+7 (sets 2,3), <36 always
            load_x_bas(kc + 5, x3);
            uint4 wa0, wb0, wa1, wb1;
            if (w < 4) {
                expand_bas(x0, wa0, wb0); expand_bas(x1, wa1, wb1);
                write_a(&As[0][0], wa0, wb0); write_a(&As[1][0], wa1, wb1);
                mfma_chunk(&As[2][0], bE);
                load_b(kc + 2, bE);
                mfma_chunk(&As[3][0], bO);
            } else {
                mfma_chunk(&As[2][0], bE);
                load_b(kc + 2, bE);
                mfma_chunk(&As[3][0], bO);
                expand_bas(x0, wa0, wb0); expand_bas(x1, wa1, wb1);
                write_a(&As[0][0], wa0, wb0); write_a(&As[1][0], wa1, wb1);
            }
            block_sync_lds();
        }
        {   // even superstep: chunks kc2,kc2+1 = 4t+4,4t+5; read bufs 0,1; write 2,3
            const int kc2 = 4 * t + 4;
            load_b(kc2 + 1, bO);
            if (kc2 + 5 < NCHUNK) {        // skip only at t=7 (chunks 36,37)
                load_x_bas(kc2 + 4, x0);
                load_x_bas(kc2 + 5, x1);
            }
            uint4 wa0, wb0, wa1, wb1;
            if (w < 4) {
                expand_bas(x2, wa0, wb0); expand_bas(x3, wa1, wb1);
                write_a(&As[2][0], wa0, wb0); write_a(&As[3][0], wa1, wb1);
                mfma_chunk(&As[0][0], bE);
                load_b(kc2 + 2, bE);
                mfma_chunk(&As[1][0], bO);
            } else {
                mfma_chunk(&As[0][0], bE);
                load_b(kc2 + 2, bE);
                mfma_chunk(&As[1][0], bO);
                expand_bas(x2, wa0, wb0); expand_bas(x3, wa1, wb1);
                write_a(&As[2][0], wa0, wb0); write_a(&As[3][0], wa1, wb1);
            }
            block_sync_lds();
        }
    }

    // ---- tail superstep 17: chunks 34,35 (bufs 2,3), no expand ----
    load_b(35, bO);
    mfma_chunk(&As[2][0], bE);             // bE = b(34), loaded in t=7 even body
    mfma_chunk(&As[3][0], bO);

    // epilogue: C/D layout col = lane&15, row = (lane>>4)*4 + reg
#pragma unroll
    for (int mt = 0; mt < 4; ++mt) {
        int row = row0 + wm * 64 + mt * 16 + q * 4;
#pragma unroll
        for (int nt = 0; nt < 4; ++nt) {
            int col = wn * 64 + nt * 16 + l15;
#pragma unroll
            for (int r = 0; r < 4; ++r)
                out[(size_t)(row + r) * OUT_F + col] = acc[mt][nt][r];
        }
    }
}

extern "C" void kernel_launch(void* const* d_in, const int* in_sizes, int n_in,
                              void* d_out, int out_size, void* d_ws, size_t ws_size,
                              hipStream_t stream) {
    const float* x  = (const float*)d_in[0];
    const float* bw = (const float*)d_in[1];
    const float* sw = (const float*)d_in[2];
    const float* ss = (const float*)d_in[3];
    unsigned short* WcF = (unsigned short*)d_ws;                // 1.18 MB

    build_w<<<dim3(OUT_F), dim3(IN_F), 0, stream>>>(bw, sw, ss, WcF);

    const int B_ROWS = in_sizes[0] / IN_F;                      // 32768
    kan_fused<<<dim3(B_ROWS / 128), dim3(512), 0, stream>>>(
        x, WcF, (float*)d_out);
}